// Round 11
// baseline (167.968 us; speedup 1.0000x reference)
//
#include <hip/hip_runtime.h>
#include <math.h>

#define KK 9
#define BB 8
#define CC 64
#define OO 64
#define HH 128
#define WW 128
#define HWSZ (HH*WW)

typedef _Float16 half8 __attribute__((ext_vector_type(8)));
typedef float    floatx4 __attribute__((ext_vector_type(4)));

// ws layout (f16): Wp[9][2][4][32][8] | Wd[9][2][4][64][8] | x_h[B][HW][64]
// Frag order: element (k, ks, quad, n, e) holds W[n][c] with c = ks*32 + quad*8 + e
#define WP_ELEMS (9*2*4*32*8)   // 18432 elements
#define WD_ELEMS (9*2*4*64*8)   // 36864 elements
#define XH_ELEMS ((size_t)BB*HWSZ*64)
#define NCONV 2048

// ---------------- prep: x -> channel-last f16 (+ weight repack, frag-ordered) ----------------
__global__ __launch_bounds__(256) void prep(
    const float* __restrict__ x,
    const float* __restrict__ p_w, const float* __restrict__ m_w,
    const float* __restrict__ d_w,
    _Float16* __restrict__ Wp, _Float16* __restrict__ Wd, _Float16* __restrict__ x_h,
    int conv_blocks)
{
    const int blk = blockIdx.x;
    const int tid = threadIdx.x;
    if (blk < conv_blocks) {
        __shared__ _Float16 sh[64][72];
        const int b    = blk >> 8;
        const int pix0 = (blk & 255) * 64;
        const float* xb = x + (size_t)b*CC*HWSZ + pix0;
        {
            const int f  = tid & 15;        // float4 index within 64 px
            const int c0 = tid >> 4;        // 0..15
            #pragma unroll
            for (int j = 0; j < 4; ++j) {
                const int c = j*16 + c0;
                const floatx4 v = *(const floatx4*)(xb + (size_t)c*HWSZ + f*4);
                sh[f*4+0][c] = (_Float16)v[0];
                sh[f*4+1][c] = (_Float16)v[1];
                sh[f*4+2][c] = (_Float16)v[2];
                sh[f*4+3][c] = (_Float16)v[3];
            }
        }
        __syncthreads();
        {
            const int p  = tid >> 2;
            const int c0 = (tid & 3) * 16;
            _Float16* dst = x_h + ((size_t)b*HWSZ + pix0 + p)*64 + c0;
            *(half8*)dst       = *(const half8*)&sh[p][c0];
            *(half8*)(dst + 8) = *(const half8*)&sh[p][c0 + 8];
        }
    } else {
        const int i = (blk - conv_blocks)*256 + tid;
        if (i < WP_ELEMS) {
            // i -> [k][ks][quad][n][e]
            const int e = i & 7, n = (i>>3)&31, quad = (i>>8)&3, ks = (i>>10)&1, k = i>>11;
            const int c = ks*32 + quad*8 + e;
            float v = 0.f;
            if (n < 18)      v = p_w[(n*CC + c)*KK + k];
            else if (n < 27) v = m_w[((n-18)*CC + c)*KK + k];
            Wp[i] = (_Float16)v;
        } else if (i < WP_ELEMS + WD_ELEMS) {
            const int j = i - WP_ELEMS;
            // j -> [k][ks][quad][o][e]
            const int e = j & 7, o = (j>>3)&63, quad = (j>>9)&3, ks = (j>>11)&1, k = j>>12;
            const int c = ks*32 + quad*8 + e;
            Wd[j] = (_Float16)d_w[(o*CC + c)*KK + k];
        }
    }
}

// ---------------- fused DCNv2: asm-pinned gathers + counted vmcnt (T4), LDS weights ---------
// grid 2048 (b = blk&7 XCD swizzle, seg -> 64-pixel half-row); block 256 = 4 waves.
// Phase 2 = 2 straight-line ks-passes (channel halves). Per pass: Wd-half (36.9KB) staged in
// LDS (lgkmcnt domain -> no vmcnt interference); per tap 4x16B coalesced gathers issued via
// inline-asm global_load_dwordx4 (compiler cannot sink them), consumed after counted
// s_waitcnt vmcnt(8) with data-dependence ties -> 12 loads in flight, 3 taps of latency hiding.
// R7 proved HIP loads get sunk (depth 1.25); R8 proved sched_barrier(0) over-serializes.
__global__ __launch_bounds__(256, 3) void dcn_fused(
    const _Float16* __restrict__ x_h,
    const _Float16* __restrict__ Wp, const _Float16* __restrict__ Wd,
    const float* __restrict__ p_b, const float* __restrict__ m_b,
    const float* __restrict__ db,
    float* __restrict__ out, float* __restrict__ offset_out)
{
    __shared__ alignas(16) char smem[9*2048*2];   // 36864 B; T (7.3KB) and T2 alias it
    _Float16* WL = (_Float16*)smem;
    float*    T  = (float*)smem;                  // [27][68] conv1 out (bias folded)

    const int tid  = threadIdx.x;
    const int wv   = tid >> 6;
    const int lane = tid & 63;
    const int quad = lane >> 4;
    const int l15  = lane & 15;
    const int b    = blockIdx.x & 7;
    const int seg  = blockIdx.x >> 3;      // 0..255
    const int row  = seg >> 1;
    const int col0 = (seg & 1) * 64;
    const int pix0 = row * WW + col0;
    const _Float16* xbh = x_h + (size_t)b*HWSZ*64;

    // gather-order identity for this lane (both phases):
    const int p2   = wv*16 + (lane >> 2);   // pixel this lane gathers/combines
    const int part = lane & 3;              // 16B part within the record slice
    const int wx2  = col0 + p2;
    // bpermute byte-index: MFMA lane m pulls from gather lane ((m&15)<<2)|(m>>4)
    const int bidx = ((l15 << 2) | quad) << 2;

    union U { half8 h; int i[4]; };

    // =============== phase 1: offset(18)+mask(9) conv — pixel-major, plain HIP (R7) =========
    floatx4 accp[2];
    accp[0] = (floatx4)0.f; accp[1] = (floatx4)0.f;
    #pragma unroll
    for (int k = 0; k < 9; ++k) {
        const int hy = row + k/3 - 1;
        const int hx = wx2 + k%3 - 1;
        const bool vld = (hy >= 0) & (hy < HH) & (hx >= 0) & (hx < WW);
        const _Float16* ap = xbh + (size_t)(vld ? hy*WW + hx : 0)*64 + part*8;
        const half8 z = (half8)(_Float16)0.f;
        half8 a0 = *(const half8*)ap;
        half8 a1 = *(const half8*)(ap + 32);
        a0 = vld ? a0 : z;
        a1 = vld ? a1 : z;
        U u0, u1, b0, b1;
        u0.h = a0; u1.h = a1;
        #pragma unroll
        for (int d = 0; d < 4; ++d) {
            b0.i[d] = __builtin_amdgcn_ds_bpermute(bidx, u0.i[d]);
            b1.i[d] = __builtin_amdgcn_ds_bpermute(bidx, u1.i[d]);
        }
        const _Float16* wp = Wp + k*2048 + quad*256 + l15*8;
        accp[0] = __builtin_amdgcn_mfma_f32_16x16x32_f16(b0.h, *(const half8*)(wp),              accp[0], 0, 0, 0);
        accp[1] = __builtin_amdgcn_mfma_f32_16x16x32_f16(b0.h, *(const half8*)(wp + 128),        accp[1], 0, 0, 0);
        accp[0] = __builtin_amdgcn_mfma_f32_16x16x32_f16(b1.h, *(const half8*)(wp + 1024),       accp[0], 0, 0, 0);
        accp[1] = __builtin_amdgcn_mfma_f32_16x16x32_f16(b1.h, *(const half8*)(wp + 1024 + 128), accp[1], 0, 0, 0);
    }

    // epilogue 1: D-frags -> T (bias folded), one barrier
    #pragma unroll
    for (int nt = 0; nt < 2; ++nt) {
        const int ch = nt*16 + l15;
        if (ch < 27) {
            const float bias = (ch < 18) ? p_b[ch] : m_b[ch-18];
            #pragma unroll
            for (int r = 0; r < 4; ++r)
                T[ch*68 + wv*16 + quad*4 + r] = accp[nt][r] + bias;
        }
    }
    __syncthreads();

    // offsets -> global + sampling params to regs (T is consumed HERE; WL overwrites it later)
    {
        float* offp = offset_out + (size_t)b*18*HWSZ + pix0;
        #pragma unroll
        for (int j = 0; j < 5; ++j) {
            const int idx = j*256 + tid;
            if (idx < 18*64) {
                const int ch = idx >> 6, pp = idx & 63;
                offp[ch*HWSZ + pp] = T[ch*68 + pp];
            }
        }
    }
    float dyk[9], dxk[9], mkk[9];
    #pragma unroll
    for (int k = 0; k < 9; ++k) {
        dyk[k] = T[(2*k  )*68 + p2];
        dxk[k] = T[(2*k+1)*68 + p2];
        mkk[k] = 1.f / (1.f + expf(-T[(18+k)*68 + p2]));
    }
    __syncthreads();   // all T reads done before WL staging overwrites the aliased smem

    // =============== phase 2: 2 ks-passes, asm-pinned 3-deep gather pipeline =================
    floatx4 acc[4];
    #pragma unroll
    for (int nt = 0; nt < 4; ++nt) acc[nt] = (floatx4)0.f;

    half8 GA[4], GB[4], GC[4];
    _Float16 gA[4], gB[4], gC[4];

    // stage Wd half KS into WL: 2304 x 16B chunks, straight-line (R6's indices, no runtime loop)
    #define STAGE(KS) do {                                                          \
        _Pragma("unroll")                                                           \
        for (int j = 0; j < 9; ++j) {                                               \
            const int c   = j*256 + tid;                                            \
            const int kk  = c >> 8;                                                 \
            const int rem = c & 255;                                                \
            *(half8*)&WL[kk*2048 + rem*8] =                                         \
                *(const half8*)(Wd + kk*4096 + (KS)*2048 + rem*8);                  \
        }                                                                           \
    } while (0)

    // issue tap kk's 4 corner gathers (one ks-half slice) via inline asm (unsinkable)
    #define GISSUE(kk, G, g, KS) do {                                               \
        const float py  = (float)(row - 1 + (kk)/3) + dyk[kk];                      \
        const float pxf = (float)(wx2 - 1 + (kk)%3) + dxk[kk];                      \
        const float y0f = floorf(py), x0f = floorf(pxf);                            \
        const int   iy0 = (int)y0f,   ix0 = (int)x0f;                               \
        const float wy1 = py - y0f,   wx1 = pxf - x0f;                              \
        const float wy0 = 1.f - wy1,  wx0 = 1.f - wx1;                              \
        const bool vy0 = ((unsigned)iy0     < (unsigned)HH);                        \
        const bool vy1 = ((unsigned)(iy0+1) < (unsigned)HH);                        \
        const bool vx0 = ((unsigned)ix0     < (unsigned)WW);                        \
        const bool vx1 = ((unsigned)(ix0+1) < (unsigned)WW);                        \
        const int cy0 = min(max(iy0,   0), HH-1), cy1 = min(max(iy0+1, 0), HH-1);   \
        const int cx0 = min(max(ix0,   0), WW-1), cx1 = min(max(ix0+1, 0), WW-1);   \
        const float mk = mkk[kk];                                                   \
        g[0] = (_Float16)(wy0*wx0*((vy0&vx0) ? mk : 0.f));                          \
        g[1] = (_Float16)(wy0*wx1*((vy0&vx1) ? mk : 0.f));                          \
        g[2] = (_Float16)(wy1*wx0*((vy1&vx0) ? mk : 0.f));                          \
        g[3] = (_Float16)(wy1*wx1*((vy1&vx1) ? mk : 0.f));                          \
        const _Float16* c0p = xbh + (size_t)(cy0*WW+cx0)*64 + (KS)*32 + part*8;     \
        const _Float16* c1p = xbh + (size_t)(cy0*WW+cx1)*64 + (KS)*32 + part*8;     \
        const _Float16* c2p = xbh + (size_t)(cy1*WW+cx0)*64 + (KS)*32 + part*8;     \
        const _Float16* c3p = xbh + (size_t)(cy1*WW+cx1)*64 + (KS)*32 + part*8;     \
        asm volatile("global_load_dwordx4 %0, %1, off" : "=v"(G[0]) : "v"(c0p));    \
        asm volatile("global_load_dwordx4 %0, %1, off" : "=v"(G[1]) : "v"(c1p));    \
        asm volatile("global_load_dwordx4 %0, %1, off" : "=v"(G[2]) : "v"(c2p));    \
        asm volatile("global_load_dwordx4 %0, %1, off" : "=v"(G[3]) : "v"(c3p));    \
    } while (0)

    // counted waits with data-dependence ties (consume can't hoist above them)
    #define GW8(G) asm volatile("s_waitcnt vmcnt(8)"  : "+v"(G[0]),"+v"(G[1]),"+v"(G[2]),"+v"(G[3]))
    #define GW4(G) asm volatile("s_waitcnt vmcnt(4)"  : "+v"(G[0]),"+v"(G[1]),"+v"(G[2]),"+v"(G[3]))
    #define GW0(G) asm volatile("s_waitcnt vmcnt(0)"  : "+v"(G[0]),"+v"(G[1]),"+v"(G[2]),"+v"(G[3]) :: "memory")

    // combine, bpermute to MFMA order, 4 MFMAs with LDS weights (lgkmcnt domain)
    #define GCONS(kk, G, g) do {                                                    \
        const half8 lo = G[0]*g[0] + G[1]*g[1] + G[2]*g[2] + G[3]*g[3];             \
        U ulo, au;  ulo.h = lo;                                                     \
        _Pragma("unroll")                                                           \
        for (int d = 0; d < 4; ++d)                                                 \
            au.i[d] = __builtin_amdgcn_ds_bpermute(bidx, ulo.i[d]);                 \
        const _Float16* wdp = &WL[(kk)*2048 + quad*512 + l15*8];                    \
        _Pragma("unroll")                                                           \
        for (int nt = 0; nt < 4; ++nt)                                              \
            acc[nt] = __builtin_amdgcn_mfma_f32_16x16x32_f16(au.h, *(const half8*)(wdp + nt*128), acc[nt], 0, 0, 0); \
    } while (0)

    #define PASS(KS) do {                                                           \
        STAGE(KS);                                                                  \
        __syncthreads();                                                            \
        GISSUE(0, GA, gA, KS);  GISSUE(1, GB, gB, KS);  GISSUE(2, GC, gC, KS);      \
        GW8(GA); GCONS(0, GA, gA);  GISSUE(3, GA, gA, KS);                          \
        GW8(GB); GCONS(1, GB, gB);  GISSUE(4, GB, gB, KS);                          \
        GW8(GC); GCONS(2, GC, gC);  GISSUE(5, GC, gC, KS);                          \
        GW8(GA); GCONS(3, GA, gA);  GISSUE(6, GA, gA, KS);                          \
        GW8(GB); GCONS(4, GB, gB);  GISSUE(7, GB, gB, KS);                          \
        GW8(GC); GCONS(5, GC, gC);  GISSUE(8, GC, gC, KS);                          \
        GW8(GA); GCONS(6, GA, gA);                                                  \
        GW4(GB); GCONS(7, GB, gB);                                                  \
        GW0(GC); GCONS(8, GC, gC);                                                  \
    } while (0)

    PASS(0);
    __syncthreads();   // pass-0 WL readers done before restage
    PASS(1);

    #undef STAGE
    #undef GISSUE
    #undef GW8
    #undef GW4
    #undef GW0
    #undef GCONS
    #undef PASS

    // epilogue 2: 4 chunks of 16 output channels via LDS transpose (aliases smem)
    __syncthreads();
    float* T2 = (float*)smem;   // [16][68]
    #pragma unroll
    for (int oc = 0; oc < 4; ++oc) {
        #pragma unroll
        for (int r = 0; r < 4; ++r)
            T2[l15*68 + wv*16 + quad*4 + r] = acc[oc][r];
        __syncthreads();
        #pragma unroll
        for (int j = 0; j < 4; ++j) {
            const int idx = j*256 + tid;
            const int o16 = idx >> 6, pp = idx & 63;
            out[((size_t)b*OO + oc*16 + o16)*HWSZ + pix0 + pp] = T2[o16*68 + pp] + db[oc*16 + o16];
        }
        __syncthreads();
    }
}

// ---------------- fallback (ws too small): R5-style LDS kernel, fp32 gather ----------------
__global__ __launch_bounds__(256, 4) void dcn_fused_lds(
    const float* __restrict__ x,
    const _Float16* __restrict__ Wp, const _Float16* __restrict__ Wd,
    const float* __restrict__ p_b, const float* __restrict__ m_b,
    const float* __restrict__ db,
    float* __restrict__ out, float* __restrict__ offset_out)
{
    __shared__ alignas(16) _Float16 A_sh[128][72];
    __shared__ alignas(16) _Float16 WM_sh[32*72];
    __shared__ alignas(16) _Float16 Wd_sh[64][72];

    const int tid   = threadIdx.x;
    const int wv    = tid >> 6;
    const int lane  = tid & 63;
    const int quad  = lane >> 4;
    const int l15   = lane & 15;
    const int b     = blockIdx.x & 7;
    const int row   = blockIdx.x >> 3;
    const int pix0  = row * WW;
    const int p     = tid & 127;
    const int chalf = (tid >> 7) * 32;
    const int h = row, w = p;
    const float* xb = x + (size_t)b*CC*HWSZ;
    _Float16 (*W_sh)[72] = (_Float16 (*)[72])WM_sh;

    floatx4 accp[2][2];
    #pragma unroll
    for (int mt = 0; mt < 2; ++mt)
        #pragma unroll
        for (int nt = 0; nt < 2; ++nt) accp[mt][nt] = (floatx4)0.f;

    for (int k = 0; k < 9; ++k) {
        {
            const int n  = tid >> 3;
            const int c0 = (tid & 7) * 8;
            *(half8*)&W_sh[n][c0] =
                *(const half8*)(Wp + k*2048 + (c0>>5)*1024 + ((c0>>3)&3)*256 + n*8);
        }
        const int hy = h + (k/3) - 1;
        const int wx = w + (k%3) - 1;
        const bool vld = (hy >= 0) & (hy < HH) & (wx >= 0) & (wx < WW);
        const float* xs = xb + hy*WW + wx;
        #pragma unroll
        for (int cb = 0; cb < 4; ++cb) {
            union { half8 v; _Float16 e[8]; } u;
            #pragma unroll
            for (int j = 0; j < 8; ++j)
                u.e[j] = (_Float16)(vld ? xs[(size_t)(chalf + cb*8 + j)*HWSZ] : 0.f);
            *(half8*)&A_sh[p][chalf + cb*8] = u.v;
        }
        __syncthreads();
        #pragma unroll
        for (int ks = 0; ks < 2; ++ks) {
            half8 bf[2];
            #pragma unroll
            for (int nt = 0; nt < 2; ++nt)
                bf[nt] = *(const half8*)&W_sh[nt*16 + l15][ks*32 + quad*8];
            #pragma unroll
            for (int mt = 0; mt < 2; ++mt) {
                half8 af = *(const half8*)&A_sh[wv*32 + mt*16 + l15][ks*32 + quad*8];
                accp[mt][0] = __builtin_amdgcn_mfma_f32_16x16x32_f16(af, bf[0], accp[mt][0], 0, 0, 0);
                accp[mt][1] = __builtin_amdgcn_mfma_f32_16x16x32_f16(af, bf[1], accp[mt][1], 0, 0, 0);
            }
        }
        __syncthreads();
    }

    float (*T)[132] = (float (*)[132])&A_sh[0][0];
    #pragma unroll
    for (int nt = 0; nt < 2; ++nt) {
        const int ch = nt*16 + l15;
        if (ch < 27) {
            #pragma unroll
            for (int mt = 0; mt < 2; ++mt)
                #pragma unroll
                for (int r = 0; r < 4; ++r)
                    T[ch][wv*32 + mt*16 + quad*4 + r] = accp[mt][nt][r];
        }
    }
    __syncthreads();

    float dyk[9], dxk[9], mkk[9];
    float* offp = offset_out + (size_t)b*18*HWSZ + pix0;
    #pragma unroll
    for (int k = 0; k < 9; ++k) {
        dyk[k] = T[2*k][p]   + p_b[2*k];
        dxk[k] = T[2*k+1][p] + p_b[2*k+1];
        mkk[k] = 1.f / (1.f + expf(-(T[18+k][p] + m_b[k])));
    }
    if (tid < 128) {
        #pragma unroll
        for (int k = 0; k < 9; ++k) {
            offp[(2*k  )*HWSZ + p] = dyk[k];
            offp[(2*k+1)*HWSZ + p] = dxk[k];
        }
    }
    __syncthreads();

    floatx4 acc[2][4];
    #pragma unroll
    for (int mt = 0; mt < 2; ++mt)
        #pragma unroll
        for (int nt = 0; nt < 4; ++nt) acc[mt][nt] = (floatx4)0.f;

    for (int k = 0; k < 9; ++k) {
        {
            const int o  = tid >> 2;
            const int c0 = (tid & 3) * 16;
            *(half8*)&Wd_sh[o][c0] =
                *(const half8*)(Wd + k*4096 + (c0>>5)*2048 + ((c0>>3)&3)*512 + o*8);
            const int c8 = c0 + 8;
            *(half8*)&Wd_sh[o][c8] =
                *(const half8*)(Wd + k*4096 + (c8>>5)*2048 + ((c8>>3)&3)*512 + o*8);
        }
        const float mk = mkk[k];
        const float py = (float)(h - 1 + k/3) + dyk[k];
        const float px = (float)(w - 1 + k%3) + dxk[k];
        const float y0f = floorf(py), x0f = floorf(px);
        const int   iy0 = (int)y0f,   ix0 = (int)x0f;
        const float wy1 = py - y0f,   wx1 = px - x0f;
        const float wy0 = 1.f - wy1,  wx0 = 1.f - wx1;
        const bool vy0 = (iy0   >= 0) & (iy0   < HH);
        const bool vy1 = (iy0+1 >= 0) & (iy0+1 < HH);
        const bool vx0 = (ix0   >= 0) & (ix0   < WW);
        const bool vx1 = (ix0+1 >= 0) & (ix0+1 < WW);
        const int cy0 = min(max(iy0,   0), HH-1), cy1 = min(max(iy0+1, 0), HH-1);
        const int cx0 = min(max(ix0,   0), WW-1), cx1 = min(max(ix0+1, 0), WW-1);
        const int i0 = cy0*WW+cx0; const float w0 = wy0*wx0*((vy0&vx0) ? mk : 0.f);
        const int i1 = cy0*WW+cx1; const float w1 = wy0*wx1*((vy0&vx1) ? mk : 0.f);
        const int i2 = cy1*WW+cx0; const float w2 = wy1*wx0*((vy1&vx0) ? mk : 0.f);
        const int i3 = cy1*WW+cx1; const float w3 = wy1*wx1*((vy1&vx1) ? mk : 0.f);
        #pragma unroll
        for (int cb = 0; cb < 4; ++cb) {
            union { half8 v; _Float16 e[8]; } u;
            #pragma unroll
            for (int j = 0; j < 8; ++j) {
                const float* xc = xb + (size_t)(chalf + cb*8 + j)*HWSZ;
                u.e[j] = (_Float16)(w0*xc[i0] + w1*xc[i1] + w2*xc[i2] + w3*xc[i3]);
            }
            *(half8*)&A_sh[p][chalf + cb*8] = u.v;
        }
        __syncthreads();
        #pragma unroll
        for (int ks = 0; ks < 2; ++ks) {
            half8 bf[4];
            #pragma unroll
            for (int nt = 0; nt < 4; ++nt)
                bf[nt] = *(const half8*)&Wd_sh[nt*16 + l15][ks*32 + quad*8];
            #pragma unroll
            for (int mt = 0; mt < 2; ++mt) {
                half8 af = *(const half8*)&A_sh[wv*32 + mt*16 + l15][ks*32 + quad*8];
                #pragma unroll
                for (int nt = 0; nt < 4; ++nt)
                    acc[mt][nt] = __builtin_amdgcn_mfma_f32_16x16x32_f16(af, bf[nt], acc[mt][nt], 0, 0, 0);
            }
        }
        __syncthreads();
    }

    float (*T2)[132] = (float (*)[132])&A_sh[0][0];
    #pragma unroll
    for (int oc = 0; oc < 4; ++oc) {
        #pragma unroll
        for (int mt = 0; mt < 2; ++mt)
            #pragma unroll
            for (int r = 0; r < 4; ++r)
                T2[l15][wv*32 + mt*16 + quad*4 + r] = acc[mt][oc][r];
        __syncthreads();
        #pragma unroll
        for (int j = 0; j < 8; ++j) {
            const int idx = tid + j*256;
            const int o16 = idx >> 7, pp = idx & 127;
            out[((size_t)b*OO + oc*16 + o16)*HWSZ + pix0 + pp] = T2[o16][pp] + db[oc*16 + o16];
        }
        __syncthreads();
    }
}

extern "C" void kernel_launch(void* const* d_in, const int* in_sizes, int n_in,
                              void* d_out, int out_size, void* d_ws, size_t ws_size,
                              hipStream_t stream) {
    const float* x   = (const float*)d_in[0];
    const float* p_w = (const float*)d_in[1];
    const float* p_b = (const float*)d_in[2];
    const float* m_w = (const float*)d_in[3];
    const float* m_b = (const float*)d_in[4];
    const float* dw  = (const float*)d_in[5];
    const float* db  = (const float*)d_in[6];

    float* out        = (float*)d_out;             // (B,O,H,W)
    float* offset_out = out + (size_t)BB*OO*HWSZ;  // (B,18,H,W)

    _Float16* Wp  = (_Float16*)d_ws;
    _Float16* Wd  = Wp + WP_ELEMS;
    _Float16* x_h = Wd + WD_ELEMS;

    const int nrep = (WP_ELEMS + WD_ELEMS + 255) / 256;
    const size_t need = (size_t)(WP_ELEMS + WD_ELEMS + XH_ELEMS) * sizeof(_Float16);
    if (ws_size >= need) {
        prep<<<dim3(NCONV + nrep), 256, 0, stream>>>(x, p_w, m_w, dw, Wp, Wd, x_h, NCONV);
        dcn_fused<<<dim3(256*BB), 256, 0, stream>>>(x_h, Wp, Wd, p_b, m_b, db, out, offset_out);
    } else {
        prep<<<dim3(nrep), 256, 0, stream>>>(x, p_w, m_w, dw, Wp, Wd, x_h, 0);
        dcn_fused_lds<<<dim3(128*BB), 256, 0, stream>>>(x, Wp, Wd, p_b, m_b, db, out, offset_out);
    }
}

// Round 12
// 148.777 us; speedup vs baseline: 1.1290x; 1.1290x over previous
//
#include <hip/hip_runtime.h>
#include <math.h>

#define KK 9
#define BB 8
#define CC 64
#define OO 64
#define HH 128
#define WW 128
#define HWSZ (HH*WW)

typedef _Float16 half8 __attribute__((ext_vector_type(8)));
typedef float    floatx4 __attribute__((ext_vector_type(4)));

// ws layout (f16): Wp[9][2][4][32][8] | Wd[9][2][4][64][8] | x_h[B][HW][64]
// Frag order: element (k, ks, quad, n, e) holds W[n][c] with c = ks*32 + quad*8 + e
#define WP_ELEMS (9*2*4*32*8)   // 18432 elements
#define WD_ELEMS (9*2*4*64*8)   // 36864 elements
#define XH_ELEMS ((size_t)BB*HWSZ*64)
#define NCONV 2048

// ---------------- prep: x -> channel-last f16 (+ weight repack, frag-ordered) ----------------
// conv part uses float4 reads: 4 vector loads/thread (was 16 scalar f32 loads).
__global__ __launch_bounds__(256) void prep(
    const float* __restrict__ x,
    const float* __restrict__ p_w, const float* __restrict__ m_w,
    const float* __restrict__ d_w,
    _Float16* __restrict__ Wp, _Float16* __restrict__ Wd, _Float16* __restrict__ x_h,
    int conv_blocks)
{
    const int blk = blockIdx.x;
    const int tid = threadIdx.x;
    if (blk < conv_blocks) {
        __shared__ _Float16 sh[64][72];
        const int b    = blk >> 8;
        const int pix0 = (blk & 255) * 64;
        const float* xb = x + (size_t)b*CC*HWSZ + pix0;
        {
            const int f  = tid & 15;        // float4 index within 64 px
            const int c0 = tid >> 4;        // 0..15
            #pragma unroll
            for (int j = 0; j < 4; ++j) {
                const int c = j*16 + c0;
                const floatx4 v = *(const floatx4*)(xb + (size_t)c*HWSZ + f*4);
                sh[f*4+0][c] = (_Float16)v[0];
                sh[f*4+1][c] = (_Float16)v[1];
                sh[f*4+2][c] = (_Float16)v[2];
                sh[f*4+3][c] = (_Float16)v[3];
            }
        }
        __syncthreads();
        {
            const int p  = tid >> 2;
            const int c0 = (tid & 3) * 16;
            _Float16* dst = x_h + ((size_t)b*HWSZ + pix0 + p)*64 + c0;
            *(half8*)dst       = *(const half8*)&sh[p][c0];
            *(half8*)(dst + 8) = *(const half8*)&sh[p][c0 + 8];
        }
    } else {
        const int i = (blk - conv_blocks)*256 + tid;
        if (i < WP_ELEMS) {
            // i -> [k][ks][quad][n][e]
            const int e = i & 7, n = (i>>3)&31, quad = (i>>8)&3, ks = (i>>10)&1, k = i>>11;
            const int c = ks*32 + quad*8 + e;
            float v = 0.f;
            if (n < 18)      v = p_w[(n*CC + c)*KK + k];
            else if (n < 27) v = m_w[((n-18)*CC + c)*KK + k];
            Wp[i] = (_Float16)v;
        } else if (i < WP_ELEMS + WD_ELEMS) {
            const int j = i - WP_ELEMS;
            // j -> [k][ks][quad][o][e]
            const int e = j & 7, o = (j>>3)&63, quad = (j>>9)&3, ks = (j>>11)&1, k = j>>12;
            const int c = ks*32 + quad*8 + e;
            Wd[j] = (_Float16)d_w[(o*CC + c)*KK + k];
        }
    }
}

// ---------------- fused DCNv2 (R7 structure, best measured: 63.2 us) ------------------------
// grid 2048 (b = blk&7 XCD swizzle, seg -> 64-pixel half-row); block 256 = 4 waves.
// Gather lane map: lane l handles pixel (l>>2), 16B part (l&3) -> 4-lane group = one 64B line.
// ds_bpermute restores MFMA A-fragment order in-register (bijective, bit-identical).
// Phase 2 hand-pipelined 2 taps deep, compiler-scheduled. Ledger of falsified alternatives:
//   sched_barrier(0) pinning (R8: -30%), asm loads + counted vmcnt + LDS weights (R11: -34%,
//   scratch spills), LDS weight dbuf + per-tap barrier (R3: equal), no-barrier global weights
//   at higher occupancy (R4: -4%). The compiler's partially-sunk schedule is the optimum here.
__global__ __launch_bounds__(256, 3) void dcn_fused(
    const _Float16* __restrict__ x_h,
    const _Float16* __restrict__ Wp, const _Float16* __restrict__ Wd,
    const float* __restrict__ p_b, const float* __restrict__ m_b,
    const float* __restrict__ db,
    float* __restrict__ out, float* __restrict__ offset_out)
{
    __shared__ alignas(16) float T[27*68];   // conv1 out (bias folded), 7344 B; T2 aliases

    const int tid  = threadIdx.x;
    const int wv   = tid >> 6;
    const int lane = tid & 63;
    const int quad = lane >> 4;
    const int l15  = lane & 15;
    const int b    = blockIdx.x & 7;
    const int seg  = blockIdx.x >> 3;      // 0..255
    const int row  = seg >> 1;
    const int col0 = (seg & 1) * 64;
    const int pix0 = row * WW + col0;
    const _Float16* xbh = x_h + (size_t)b*HWSZ*64;

    // gather-order identity for this lane (both phases):
    const int p2   = wv*16 + (lane >> 2);   // pixel this lane gathers/combines
    const int part = lane & 3;              // 16B part within the pixel's 128B record
    const int wx2  = col0 + p2;
    // bpermute byte-index: MFMA lane m pulls from gather lane ((m&15)<<2)|(m>>4)
    const int bidx = ((l15 << 2) | quad) << 2;

    union U { half8 h; int i[4]; };

    // =============== phase 1: offset(18)+mask(9) conv — pixel-major, no LDS, no barriers ====
    floatx4 accp[2];
    accp[0] = (floatx4)0.f; accp[1] = (floatx4)0.f;
    #pragma unroll
    for (int k = 0; k < 9; ++k) {
        const int hy = row + k/3 - 1;
        const int hx = wx2 + k%3 - 1;
        const bool vld = (hy >= 0) & (hy < HH) & (hx >= 0) & (hx < WW);
        const _Float16* ap = xbh + (size_t)(vld ? hy*WW + hx : 0)*64 + part*8;
        const half8 z = (half8)(_Float16)0.f;
        half8 a0 = *(const half8*)ap;
        half8 a1 = *(const half8*)(ap + 32);
        a0 = vld ? a0 : z;
        a1 = vld ? a1 : z;
        U u0, u1, b0, b1;
        u0.h = a0; u1.h = a1;
        #pragma unroll
        for (int d = 0; d < 4; ++d) {
            b0.i[d] = __builtin_amdgcn_ds_bpermute(bidx, u0.i[d]);
            b1.i[d] = __builtin_amdgcn_ds_bpermute(bidx, u1.i[d]);
        }
        const _Float16* wp = Wp + k*2048 + quad*256 + l15*8;
        accp[0] = __builtin_amdgcn_mfma_f32_16x16x32_f16(b0.h, *(const half8*)(wp),              accp[0], 0, 0, 0);
        accp[1] = __builtin_amdgcn_mfma_f32_16x16x32_f16(b0.h, *(const half8*)(wp + 128),        accp[1], 0, 0, 0);
        accp[0] = __builtin_amdgcn_mfma_f32_16x16x32_f16(b1.h, *(const half8*)(wp + 1024),       accp[0], 0, 0, 0);
        accp[1] = __builtin_amdgcn_mfma_f32_16x16x32_f16(b1.h, *(const half8*)(wp + 1024 + 128), accp[1], 0, 0, 0);
    }

    // epilogue 1: D-frags -> T (bias folded), one barrier
    #pragma unroll
    for (int nt = 0; nt < 2; ++nt) {
        const int ch = nt*16 + l15;
        if (ch < 27) {
            const float bias = (ch < 18) ? p_b[ch] : m_b[ch-18];
            #pragma unroll
            for (int r = 0; r < 4; ++r)
                T[ch*68 + wv*16 + quad*4 + r] = accp[nt][r] + bias;
        }
    }
    __syncthreads();

    // offsets -> global + sampling params to regs
    {
        float* offp = offset_out + (size_t)b*18*HWSZ + pix0;
        #pragma unroll
        for (int j = 0; j < 5; ++j) {
            const int idx = j*256 + tid;
            if (idx < 18*64) {
                const int ch = idx >> 6, pp = idx & 63;
                offp[ch*HWSZ + pp] = T[ch*68 + pp];
            }
        }
    }
    float dyk[9], dxk[9], mkk[9];
    #pragma unroll
    for (int k = 0; k < 9; ++k) {
        dyk[k] = T[(2*k  )*68 + p2];
        dxk[k] = T[(2*k+1)*68 + p2];
        mkk[k] = 1.f / (1.f + expf(-T[(18+k)*68 + p2]));
    }

    // =============== phase 2: modulated deformable conv — 2-deep pipelined, no barriers =====
    floatx4 acc[4];
    #pragma unroll
    for (int nt = 0; nt < 4; ++nt) acc[nt] = (floatx4)0.f;

    half8 GA[8], GB[8];
    _Float16 gA[4], gB[4];

    // ISSUE(kk): compute tap kk's sampling coords, bilinear gains -> g[4]; fire 8 gathers -> G
    #define ISSUE(kk, G, g) do {                                                   \
        const float py  = (float)(row - 1 + (kk)/3) + dyk[kk];                     \
        const float pxf = (float)(wx2 - 1 + (kk)%3) + dxk[kk];                     \
        const float y0f = floorf(py), x0f = floorf(pxf);                           \
        const int   iy0 = (int)y0f,   ix0 = (int)x0f;                              \
        const float wy1 = py - y0f,   wx1 = pxf - x0f;                             \
        const float wy0 = 1.f - wy1,  wx0 = 1.f - wx1;                             \
        const bool vy0 = ((unsigned)iy0     < (unsigned)HH);                       \
        const bool vy1 = ((unsigned)(iy0+1) < (unsigned)HH);                       \
        const bool vx0 = ((unsigned)ix0     < (unsigned)WW);                       \
        const bool vx1 = ((unsigned)(ix0+1) < (unsigned)WW);                       \
        const int cy0 = min(max(iy0,   0), HH-1), cy1 = min(max(iy0+1, 0), HH-1);  \
        const int cx0 = min(max(ix0,   0), WW-1), cx1 = min(max(ix0+1, 0), WW-1);  \
        const float mk = mkk[kk];                                                  \
        g[0] = (_Float16)(wy0*wx0*((vy0&vx0) ? mk : 0.f));                         \
        g[1] = (_Float16)(wy0*wx1*((vy0&vx1) ? mk : 0.f));                         \
        g[2] = (_Float16)(wy1*wx0*((vy1&vx0) ? mk : 0.f));                         \
        g[3] = (_Float16)(wy1*wx1*((vy1&vx1) ? mk : 0.f));                         \
        const _Float16* c0p = xbh + (size_t)(cy0*WW+cx0)*64 + part*8;              \
        const _Float16* c1p = xbh + (size_t)(cy0*WW+cx1)*64 + part*8;              \
        const _Float16* c2p = xbh + (size_t)(cy1*WW+cx0)*64 + part*8;              \
        const _Float16* c3p = xbh + (size_t)(cy1*WW+cx1)*64 + part*8;              \
        G[0] = *(const half8*)c0p;  G[1] = *(const half8*)(c0p + 32);              \
        G[2] = *(const half8*)c1p;  G[3] = *(const half8*)(c1p + 32);              \
        G[4] = *(const half8*)c2p;  G[5] = *(const half8*)(c2p + 32);              \
        G[6] = *(const half8*)c3p;  G[7] = *(const half8*)(c3p + 32);              \
    } while (0)

    // CONSUME(kk): bilinear combine, bpermute to MFMA order, 8 MFMAs with global weights
    #define CONSUME(kk, G, g) do {                                                 \
        const half8 lo = G[0]*g[0] + G[2]*g[1] + G[4]*g[2] + G[6]*g[3];            \
        const half8 hi = G[1]*g[0] + G[3]*g[1] + G[5]*g[2] + G[7]*g[3];            \
        U ulo, uhi, a0u, a1u;                                                      \
        ulo.h = lo; uhi.h = hi;                                                    \
        _Pragma("unroll")                                                          \
        for (int d = 0; d < 4; ++d) {                                              \
            a0u.i[d] = __builtin_amdgcn_ds_bpermute(bidx, ulo.i[d]);               \
            a1u.i[d] = __builtin_amdgcn_ds_bpermute(bidx, uhi.i[d]);               \
        }                                                                          \
        const _Float16* wd0 = Wd + (kk)*4096 +        quad*512 + l15*8;            \
        const _Float16* wd1 = Wd + (kk)*4096 + 2048 + quad*512 + l15*8;            \
        _Pragma("unroll")                                                          \
        for (int nt = 0; nt < 4; ++nt)                                             \
            acc[nt] = __builtin_amdgcn_mfma_f32_16x16x32_f16(a0u.h, *(const half8*)(wd0 + nt*128), acc[nt], 0, 0, 0); \
        _Pragma("unroll")                                                          \
        for (int nt = 0; nt < 4; ++nt)                                             \
            acc[nt] = __builtin_amdgcn_mfma_f32_16x16x32_f16(a1u.h, *(const half8*)(wd1 + nt*128), acc[nt], 0, 0, 0); \
    } while (0)

    ISSUE(0, GA, gA);
    ISSUE(1, GB, gB);
    CONSUME(0, GA, gA);  ISSUE(2, GA, gA);
    CONSUME(1, GB, gB);  ISSUE(3, GB, gB);
    CONSUME(2, GA, gA);  ISSUE(4, GA, gA);
    CONSUME(3, GB, gB);  ISSUE(5, GB, gB);
    CONSUME(4, GA, gA);  ISSUE(6, GA, gA);
    CONSUME(5, GB, gB);  ISSUE(7, GB, gB);
    CONSUME(6, GA, gA);  ISSUE(8, GA, gA);
    CONSUME(7, GB, gB);
    CONSUME(8, GA, gA);

    #undef ISSUE
    #undef CONSUME

    // epilogue 2: 4 chunks of 16 output channels via LDS transpose (aliases T)
    __syncthreads();   // all waves past their T reads before overwrite
    float* T2 = T;     // [16][68]
    #pragma unroll
    for (int oc = 0; oc < 4; ++oc) {
        #pragma unroll
        for (int r = 0; r < 4; ++r)
            T2[l15*68 + wv*16 + quad*4 + r] = acc[oc][r];
        __syncthreads();
        #pragma unroll
        for (int j = 0; j < 4; ++j) {
            const int idx = j*256 + tid;
            const int o16 = idx >> 6, pp = idx & 63;
            out[((size_t)b*OO + oc*16 + o16)*HWSZ + pix0 + pp] = T2[o16*68 + pp] + db[oc*16 + o16];
        }
        __syncthreads();
    }
}

// ---------------- fallback (ws too small): R5-style LDS kernel, fp32 gather ----------------
__global__ __launch_bounds__(256, 4) void dcn_fused_lds(
    const float* __restrict__ x,
    const _Float16* __restrict__ Wp, const _Float16* __restrict__ Wd,
    const float* __restrict__ p_b, const float* __restrict__ m_b,
    const float* __restrict__ db,
    float* __restrict__ out, float* __restrict__ offset_out)
{
    __shared__ alignas(16) _Float16 A_sh[128][72];
    __shared__ alignas(16) _Float16 WM_sh[32*72];
    __shared__ alignas(16) _Float16 Wd_sh[64][72];

    const int tid   = threadIdx.x;
    const int wv    = tid >> 6;
    const int lane  = tid & 63;
    const int quad  = lane >> 4;
    const int l15   = lane & 15;
    const int b     = blockIdx.x & 7;
    const int row   = blockIdx.x >> 3;
    const int pix0  = row * WW;
    const int p     = tid & 127;
    const int chalf = (tid >> 7) * 32;
    const int h = row, w = p;
    const float* xb = x + (size_t)b*CC*HWSZ;
    _Float16 (*W_sh)[72] = (_Float16 (*)[72])WM_sh;

    floatx4 accp[2][2];
    #pragma unroll
    for (int mt = 0; mt < 2; ++mt)
        #pragma unroll
        for (int nt = 0; nt < 2; ++nt) accp[mt][nt] = (floatx4)0.f;

    for (int k = 0; k < 9; ++k) {
        {
            const int n  = tid >> 3;
            const int c0 = (tid & 7) * 8;
            *(half8*)&W_sh[n][c0] =
                *(const half8*)(Wp + k*2048 + (c0>>5)*1024 + ((c0>>3)&3)*256 + n*8);
        }
        const int hy = h + (k/3) - 1;
        const int wx = w + (k%3) - 1;
        const bool vld = (hy >= 0) & (hy < HH) & (wx >= 0) & (wx < WW);
        const float* xs = xb + hy*WW + wx;
        #pragma unroll
        for (int cb = 0; cb < 4; ++cb) {
            union { half8 v; _Float16 e[8]; } u;
            #pragma unroll
            for (int j = 0; j < 8; ++j)
                u.e[j] = (_Float16)(vld ? xs[(size_t)(chalf + cb*8 + j)*HWSZ] : 0.f);
            *(half8*)&A_sh[p][chalf + cb*8] = u.v;
        }
        __syncthreads();
        #pragma unroll
        for (int ks = 0; ks < 2; ++ks) {
            half8 bf[2];
            #pragma unroll
            for (int nt = 0; nt < 2; ++nt)
                bf[nt] = *(const half8*)&W_sh[nt*16 + l15][ks*32 + quad*8];
            #pragma unroll
            for (int mt = 0; mt < 2; ++mt) {
                half8 af = *(const half8*)&A_sh[wv*32 + mt*16 + l15][ks*32 + quad*8];
                accp[mt][0] = __builtin_amdgcn_mfma_f32_16x16x32_f16(af, bf[0], accp[mt][0], 0, 0, 0);
                accp[mt][1] = __builtin_amdgcn_mfma_f32_16x16x32_f16(af, bf[1], accp[mt][1], 0, 0, 0);
            }
        }
        __syncthreads();
    }

    float (*T)[132] = (float (*)[132])&A_sh[0][0];
    #pragma unroll
    for (int nt = 0; nt < 2; ++nt) {
        const int ch = nt*16 + l15;
        if (ch < 27) {
            #pragma unroll
            for (int mt = 0; mt < 2; ++mt)
                #pragma unroll
                for (int r = 0; r < 4; ++r)
                    T[ch][wv*32 + mt*16 + quad*4 + r] = accp[mt][nt][r];
        }
    }
    __syncthreads();

    float dyk[9], dxk[9], mkk[9];
    float* offp = offset_out + (size_t)b*18*HWSZ + pix0;
    #pragma unroll
    for (int k = 0; k < 9; ++k) {
        dyk[k] = T[2*k][p]   + p_b[2*k];
        dxk[k] = T[2*k+1][p] + p_b[2*k+1];
        mkk[k] = 1.f / (1.f + expf(-(T[18+k][p] + m_b[k])));
    }
    if (tid < 128) {
        #pragma unroll
        for (int k = 0; k < 9; ++k) {
            offp[(2*k  )*HWSZ + p] = dyk[k];
            offp[(2*k+1)*HWSZ + p] = dxk[k];
        }
    }
    __syncthreads();

    floatx4 acc[2][4];
    #pragma unroll
    for (int mt = 0; mt < 2; ++mt)
        #pragma unroll
        for (int nt = 0; nt < 4; ++nt) acc[mt][nt] = (floatx4)0.f;

    for (int k = 0; k < 9; ++k) {
        {
            const int o  = tid >> 2;
            const int c0 = (tid & 3) * 16;
            *(half8*)&Wd_sh[o][c0] =
                *(const half8*)(Wd + k*4096 + (c0>>5)*2048 + ((c0>>3)&3)*512 + o*8);
            const int c8 = c0 + 8;
            *(half8*)&Wd_sh[o][c8] =
                *(const half8*)(Wd + k*4096 + (c8>>5)*2048 + ((c8>>3)&3)*512 + o*8);
        }
        const float mk = mkk[k];
        const float py = (float)(h - 1 + k/3) + dyk[k];
        const float px = (float)(w - 1 + k%3) + dxk[k];
        const float y0f = floorf(py), x0f = floorf(px);
        const int   iy0 = (int)y0f,   ix0 = (int)x0f;
        const float wy1 = py - y0f,   wx1 = px - x0f;
        const float wy0 = 1.f - wy1,  wx0 = 1.f - wx1;
        const bool vy0 = (iy0   >= 0) & (iy0   < HH);
        const bool vy1 = (iy0+1 >= 0) & (iy0+1 < HH);
        const bool vx0 = (ix0   >= 0) & (ix0   < WW);
        const bool vx1 = (ix0+1 >= 0) & (ix0+1 < WW);
        const int cy0 = min(max(iy0,   0), HH-1), cy1 = min(max(iy0+1, 0), HH-1);
        const int cx0 = min(max(ix0,   0), WW-1), cx1 = min(max(ix0+1, 0), WW-1);
        const int i0 = cy0*WW+cx0; const float w0 = wy0*wx0*((vy0&vx0) ? mk : 0.f);
        const int i1 = cy0*WW+cx1; const float w1 = wy0*wx1*((vy0&vx1) ? mk : 0.f);
        const int i2 = cy1*WW+cx0; const float w2 = wy1*wx0*((vy1&vx0) ? mk : 0.f);
        const int i3 = cy1*WW+cx1; const float w3 = wy1*wx1*((vy1&vx1) ? mk : 0.f);
        #pragma unroll
        for (int cb = 0; cb < 4; ++cb) {
            union { half8 v; _Float16 e[8]; } u;
            #pragma unroll
            for (int j = 0; j < 8; ++j) {
                const float* xc = xb + (size_t)(chalf + cb*8 + j)*HWSZ;
                u.e[j] = (_Float16)(w0*xc[i0] + w1*xc[i1] + w2*xc[i2] + w3*xc[i3]);
            }
            *(half8*)&A_sh[p][chalf + cb*8] = u.v;
        }
        __syncthreads();
        #pragma unroll
        for (int ks = 0; ks < 2; ++ks) {
            half8 bf[4];
            #pragma unroll
            for (int nt = 0; nt < 4; ++nt)
                bf[nt] = *(const half8*)&Wd_sh[nt*16 + l15][ks*32 + quad*8];
            #pragma unroll
            for (int mt = 0; mt < 2; ++mt) {
                half8 af = *(const half8*)&A_sh[wv*32 + mt*16 + l15][ks*32 + quad*8];
                #pragma unroll
                for (int nt = 0; nt < 4; ++nt)
                    acc[mt][nt] = __builtin_amdgcn_mfma_f32_16x16x32_f16(af, bf[nt], acc[mt][nt], 0, 0, 0);
            }
        }
        __syncthreads();
    }

    float (*T2)[132] = (float (*)[132])&A_sh[0][0];
    #pragma unroll
    for (int oc = 0; oc < 4; ++oc) {
        #pragma unroll
        for (int mt = 0; mt < 2; ++mt)
            #pragma unroll
            for (int r = 0; r < 4; ++r)
                T2[l15][wv*32 + mt*16 + quad*4 + r] = acc[mt][oc][r];
        __syncthreads();
        #pragma unroll
        for (int j = 0; j < 8; ++j) {
            const int idx = tid + j*256;
            const int o16 = idx >> 7, pp = idx & 127;
            out[((size_t)b*OO + oc*16 + o16)*HWSZ + pix0 + pp] = T2[o16][pp] + db[oc*16 + o16];
        }
        __syncthreads();
    }
}

extern "C" void kernel_launch(void* const* d_in, const int* in_sizes, int n_in,
                              void* d_out, int out_size, void* d_ws, size_t ws_size,
                              hipStream_t stream) {
    const float* x   = (const float*)d_in[0];
    const float* p_w = (const float*)d_in[1];
    const float* p_b = (const float*)d_in[2];
    const float* m_w = (const float*)d_in[3];
    const float* m_b = (const float*)d_in[4];
    const float* dw  = (const float*)d_in[5];
    const float* db  = (const float*)d_in[6];

    float* out        = (float*)d_out;             // (B,O,H,W)
    float* offset_out = out + (size_t)BB*OO*HWSZ;  // (B,18,H,W)

    _Float16* Wp  = (_Float16*)d_ws;
    _Float16* Wd  = Wp + WP_ELEMS;
    _Float16* x_h = Wd + WD_ELEMS;

    const int nrep = (WP_ELEMS + WD_ELEMS + 255) / 256;
    const size_t need = (size_t)(WP_ELEMS + WD_ELEMS + XH_ELEMS) * sizeof(_Float16);
    if (ws_size >= need) {
        prep<<<dim3(NCONV + nrep), 256, 0, stream>>>(x, p_w, m_w, dw, Wp, Wd, x_h, NCONV);
        dcn_fused<<<dim3(256*BB), 256, 0, stream>>>(x_h, Wp, Wd, p_b, m_b, db, out, offset_out);
    } else {
        prep<<<dim3(nrep), 256, 0, stream>>>(x, p_w, m_w, dw, Wp, Wd, x_h, 0);
        dcn_fused_lds<<<dim3(128*BB), 256, 0, stream>>>(x, Wp, Wd, p_b, m_b, db, out, offset_out);
    }
}